// Round 1
// baseline (190.726 us; speedup 1.0000x reference)
//
#include <hip/hip_runtime.h>
#include <hip/hip_bf16.h>

// Sentence rep: out[b][d] = mean over s of in[b][s][d]
// in:  [4096, 128, 512] fp32  (1.074 GB)
// out: [4096, 512] fp32       (8.4 MB)
//
// One thread per output float4. 4096*512/4 = 524288 threads.
// Lane i of a wave reads consecutive float4s of the same row -> coalesced
// 1 KiB/wave per load. Each thread strides s=0..127 (stride 512 floats).

__global__ __launch_bounds__(256) void sentence_rep_mean_kernel(
    const float4* __restrict__ in, float4* __restrict__ out) {
    const int t = blockIdx.x * blockDim.x + threadIdx.x;  // 0..524287
    const int d4 = t & 127;                                // float4 column 0..127
    const int b  = t >> 7;                                 // batch 0..4095

    // per-batch stride in float4 units: 128*512/4 = 16384; per-seq stride: 128
    const float4* row = in + (size_t)b * 16384 + d4;

    float ax = 0.f, ay = 0.f, az = 0.f, aw = 0.f;
    #pragma unroll 8
    for (int s = 0; s < 128; ++s) {
        float4 v = row[(size_t)s * 128];
        ax += v.x; ay += v.y; az += v.z; aw += v.w;
    }

    const float scale = 1.0f / 128.0f;
    float4 r;
    r.x = ax * scale; r.y = ay * scale; r.z = az * scale; r.w = aw * scale;
    out[t] = r;
}

extern "C" void kernel_launch(void* const* d_in, const int* in_sizes, int n_in,
                              void* d_out, int out_size, void* d_ws, size_t ws_size,
                              hipStream_t stream) {
    const float4* in = (const float4*)d_in[0];
    float4* out = (float4*)d_out;
    // out_size = 4096*512 floats = 524288 float4
    const int total_f4 = out_size / 4;           // 524288
    const int block = 256;
    const int grid = (total_f4 + block - 1) / block;  // 2048
    sentence_rep_mean_kernel<<<grid, block, 0, stream>>>(in, out);
}